// Round 14
// baseline (91.203 us; speedup 1.0000x reference)
//
#include <hip/hip_runtime.h>
#include <math.h>

#define NW 192
#define Wt 193
#define CHUNK 24           // k2 per block
#define NMAIN (192*8)      // 1536 blocks -> 4 resident/CU (32 waves, 100% cap)

// cos(2*pi*num*rcpden) via HW cos (input in revolutions)
__device__ __forceinline__ float cos_revr(float num, float rcpden) {
    float rev = num * rcpden;
    rev = __builtin_amdgcn_fractf(rev);
    return __builtin_amdgcn_cosf(rev);
}

// ---------------- k_fused v14: v11 pipeline, occupancy-doubled ----------------
// Block b: k1 = b>>3, chunk c = b&7 (k2 in [24c,24c+24)). 512 thr = 8 waves.
// LDS: win 6.5K + xls 6.5K + part 16K = 29.4KB; VGPR forced <=64 via
// __launch_bounds__(512,8) -> 4 blocks/CU = 32 waves (hardware cap).
// A: win[p][c] coalesced (lane = c); 3 p per wave.               [v11]
// B: FLIP (lane = j, all 64 active; v12-proven): wave w owns p in
//    [3w,3w+3); M row j per-lane global (L1-hot), win uniform LDS
//    b128; x -> xls[p][j] (2-way bank, free).                    [v12]
// Seeds: d_k = (cos(k1 th)*P[i][j]) * cos(k th) folded.          [v11]
// D: 24 steps = 3 subs x 8; xs uniform LDS b128; part reduce.    [v11]
__global__ __launch_bounds__(512, 8) void k_fused(const float* __restrict__ grid,
                                                  const float* __restrict__ Mw,
                                                  const float* __restrict__ P,
                                                  float* __restrict__ out) {
    __shared__ float win[CHUNK * 68];   // [p][c], stride 68
    __shared__ float xls[CHUNK * 68];   // [p][j], stride 68
    __shared__ float part[4096];        // [w 8][k2slot 8][i 64] = 16 KB

    int bx = blockIdx.x;
    int k1  = bx >> 3;                  // 0..191 (8 consecutive blocks share k1)
    int k2s = (bx & 7) * CHUNK;         // 0,24,...,168
    int t = threadIdx.x;
    int lane = t & 63;
    int w = __builtin_amdgcn_readfirstlane(t >> 6);   // 0..7
    int jb = w * 8;                     // phase-D j range
    int pb3 = w * 3;                    // phase-B p range

    // ---- Phase A: window averages, coalesced (lane = channel c) ----
    {
        int c = lane;
        const float* gb  = grid + ((size_t)k1 * Wt + k2s) * 64 + c;
        const float* gb1 = gb + (size_t)Wt * 64;
        #pragma unroll
        for (int r = 0; r < 3; ++r) {
            int p = pb3 + r;            // 8 waves x 3 = 24 positions
            float s = gb[p * 64] + gb[(p + 1) * 64]
                    + gb1[p * 64] + gb1[(p + 1) * 64];
            win[p * 68 + c] = 0.25f * s;
        }
    }
    __syncthreads();                    // sync1: win visible

    // ---- Phase B (flip): lane = j; x[p][lane] for p in [pb3, pb3+3) ----
    {
        float acc[3];
        #pragma unroll
        for (int pi = 0; pi < 3; ++pi) acc[pi] = 0.f;
        const float4* Mr = (const float4*)(Mw + (size_t)lane * 64);  // own row
        #pragma unroll
        for (int q4 = 0; q4 < 4; ++q4) {
            // per-lane global b128 x4 (M row j, 16 KB total -> L1-hot)
            float4 m0 = Mr[q4 * 4 + 0];
            float4 m1 = Mr[q4 * 4 + 1];
            float4 m2 = Mr[q4 * 4 + 2];
            float4 m3 = Mr[q4 * 4 + 3];
            #pragma unroll
            for (int pi = 0; pi < 3; ++pi) {
                // wave-uniform LDS b128 broadcast (conflict-free)
                const float4* wq = (const float4*)&win[(pb3 + pi) * 68 + q4 * 16];
                float4 w0 = wq[0], w1 = wq[1], w2 = wq[2], w3 = wq[3];
                acc[pi] += w0.x * m0.x + w0.y * m0.y + w0.z * m0.z + w0.w * m0.w
                         + w1.x * m1.x + w1.y * m1.y + w1.z * m1.z + w1.w * m1.w
                         + w2.x * m2.x + w2.y * m2.y + w2.z * m2.z + w2.w * m2.w
                         + w3.x * m3.x + w3.y * m3.y + w3.z * m3.z + w3.w * m3.w;
            }
        }
        #pragma unroll
        for (int pi = 0; pi < 3; ++pi)
            xls[(pb3 + pi) * 68 + lane] = acc[pi];   // banks (4p+j)%32: 2-way
    }

    // ---- Seeds: d_k[jl] = c1v*cos(k*theta); c1v folded into seeds ----
    float A[8], ce[8], co[8];
    {
        float4 pr0 = *(const float4*)&P[lane * 64 + jb];
        float4 pr1 = *(const float4*)&P[lane * 64 + jb + 4];
        float pv[8] = {pr0.x, pr0.y, pr0.z, pr0.w, pr1.x, pr1.y, pr1.z, pr1.w};
        float k1f = (float)k1, k2f = (float)k2s;
        #pragma unroll
        for (int jl = 0; jl < 8; ++jl) {
            float T  = (float)(lane * 64 + jb + jl + 2);
            float rT = __builtin_amdgcn_rcpf(T);
            A[jl]    = 2.0f * cos_revr(1.0f, rT);
            float c1 = cos_revr(k1f, rT) * pv[jl];
            ce[jl]   = cos_revr(k2f, rT) * c1;          // d_{k2s}
            co[jl]   = cos_revr(k2f - 1.0f, rT) * c1;   // d_{k2s-1}
        }
    }
    __syncthreads();                    // sync2: xls visible

    // ---- Phase D: 3 subs x 8 k2 steps; xs = uniform LDS b128 broadcast ----
    #pragma unroll
    for (int sub = 0; sub < 3; ++sub) {
        #pragma unroll
        for (int m = 0; m < 4; ++m) {
            {   // even step: current = ce, advance co
                int s = 2 * m;
                int k2i = sub * 8 + s;
                const float4* xq = (const float4*)&xls[k2i * 68 + jb];  // uniform
                float4 q0 = xq[0], q1 = xq[1];
                float xs[8] = {q0.x, q0.y, q0.z, q0.w, q1.x, q1.y, q1.z, q1.w};
                float pa = 0.f, pb = 0.f;       // two 4-deep chains
                #pragma unroll
                for (int jl = 0; jl < 4; ++jl) {
                    pa     = fmaf(xs[jl], ce[jl], pa);
                    co[jl] = fmaf(A[jl], ce[jl], -co[jl]);
                }
                #pragma unroll
                for (int jl = 4; jl < 8; ++jl) {
                    pb     = fmaf(xs[jl], ce[jl], pb);
                    co[jl] = fmaf(A[jl], ce[jl], -co[jl]);
                }
                part[(w * 8 + s) * 64 + lane] = pa + pb;
            }
            {   // odd step: current = co, advance ce
                int s = 2 * m + 1;
                int k2i = sub * 8 + s;
                const float4* xq = (const float4*)&xls[k2i * 68 + jb];  // uniform
                float4 q0 = xq[0], q1 = xq[1];
                float xs[8] = {q0.x, q0.y, q0.z, q0.w, q1.x, q1.y, q1.z, q1.w};
                float pa = 0.f, pb = 0.f;
                #pragma unroll
                for (int jl = 0; jl < 4; ++jl) {
                    pa     = fmaf(xs[jl], co[jl], pa);
                    ce[jl] = fmaf(A[jl], co[jl], -ce[jl]);
                }
                #pragma unroll
                for (int jl = 4; jl < 8; ++jl) {
                    pb     = fmaf(xs[jl], co[jl], pb);
                    ce[jl] = fmaf(A[jl], co[jl], -ce[jl]);
                }
                part[(w * 8 + s) * 64 + lane] = pa + pb;
            }
        }
        __syncthreads();                // all 8 wave-partial slices written
        {   // reduce 8 wave-partials; 512 thr = one (k2slot,i) each; coalesced
            float r = part[t];
            #pragma unroll
            for (int ww = 1; ww < 8; ++ww) r += part[ww * 512 + t];
            out[((size_t)k1 * NW + (k2s + sub * 8 + (t >> 6))) * 64 + (t & 63)] = r;
        }
        __syncthreads();                // part reusable next sub
    }
}

extern "C" void kernel_launch(void* const* d_in, const int* in_sizes, int n_in,
                              void* d_out, int out_size, void* d_ws, size_t ws_size,
                              hipStream_t stream) {
    const float* grid = (const float*)d_in[0];   // [193,193,64]
    const float* Mw   = (const float*)d_in[1];   // [64,64]
    const float* P    = (const float*)d_in[2];   // [64,64]
    float* out = (float*)d_out;                  // [36864,64]
    (void)d_ws; (void)ws_size;                   // workspace unused

    k_fused<<<NMAIN, 512, 0, stream>>>(grid, Mw, P, out);
}

// Round 15
// 87.420 us; speedup vs baseline: 1.0433x; 1.0433x over previous
//
#include <hip/hip_runtime.h>
#include <math.h>

#define NW 192
#define Wt 193
#define CHUNK 48           // k2 per block
#define NMAIN 768          // 192 k1 x 4 chunks; 512 thr -> exactly 3 blocks/CU

// cos(2*pi*num*rcpden) via HW cos (input in revolutions)
__device__ __forceinline__ float cos_revr(float num, float rcpden) {
    float rev = num * rcpden;
    rev = __builtin_amdgcn_fractf(rev);
    return __builtin_amdgcn_cosf(rev);
}

// ---------------- k_fused v15: v11 + issue-count cuts ----------------
// Block b: k1 = b>>2, chunk c = b&3 (k2 in [48c,48c+48)). 512 thr = 8 waves.
// LDS: win 13K + xls 13K + part 16K = 42.5KB -> 3 blocks/CU (24 waves).
// A: win[p][c] coalesced (lane = c).                                [v11]
// B: flip (lane = j, 64/64 lanes, 384 FMA): wave w owns p in [6w,6w+6);
//    M row j per-lane global (L1-hot); win uniform LDS b128.        [v12]
// Seeds: d_k = (cos(k1 th)*P[i][j]) * cos(k th) folded into seeds.  [v11]
// D: xs uniform LDS b128; part writes at wave-base + IMMEDIATE s*64
//    offsets (no per-step addr VALU); reduce + out via base pointers
//    with compile-time offsets.                                     [new]
__global__ __launch_bounds__(512, 4) void k_fused(const float* __restrict__ grid,
                                                  const float* __restrict__ Mw,
                                                  const float* __restrict__ P,
                                                  float* __restrict__ out) {
    __shared__ float win[CHUNK * 68];   // [p][c], stride 68
    __shared__ float xls[CHUNK * 68];   // [p][j], stride 68
    __shared__ float part[4096];        // [w 8][k2slot 8][i 64] = 16 KB

    int bx = blockIdx.x;
    int k1  = bx >> 2;                  // 0..191
    int k2s = (bx & 3) * CHUNK;         // 0,48,96,144
    int t = threadIdx.x;
    int lane = t & 63;
    int w = __builtin_amdgcn_readfirstlane(t >> 6);   // 0..7
    int jb = w * 8;                     // phase-D j range
    int pb6 = w * 6;                    // phase-B p range

    // ---- Phase A: window averages, coalesced (lane = channel c) ----
    {
        int c = lane;
        const float* gb  = grid + ((size_t)k1 * Wt + k2s) * 64 + c;
        const float* gb1 = gb + (size_t)Wt * 64;
        #pragma unroll
        for (int r = 0; r < 6; ++r) {
            int p = pb6 + r;            // 8 waves x 6 = 48 positions
            float s = gb[p * 64] + gb[(p + 1) * 64]
                    + gb1[p * 64] + gb1[(p + 1) * 64];
            win[p * 68 + c] = 0.25f * s;
        }
    }
    __syncthreads();                    // sync1: win visible

    // ---- Phase B (flip): lane = j; x[p][lane] for p in [pb6, pb6+6) ----
    {
        float acc[6];
        #pragma unroll
        for (int pi = 0; pi < 6; ++pi) acc[pi] = 0.f;
        const float4* Mr = (const float4*)(Mw + (size_t)lane * 64);  // own row
        #pragma unroll
        for (int q4 = 0; q4 < 4; ++q4) {
            float4 m0 = Mr[q4 * 4 + 0];
            float4 m1 = Mr[q4 * 4 + 1];
            float4 m2 = Mr[q4 * 4 + 2];
            float4 m3 = Mr[q4 * 4 + 3];
            #pragma unroll
            for (int pi = 0; pi < 6; ++pi) {
                const float4* wq = (const float4*)&win[(pb6 + pi) * 68 + q4 * 16];
                float4 w0 = wq[0], w1 = wq[1], w2 = wq[2], w3 = wq[3];
                acc[pi] += w0.x * m0.x + w0.y * m0.y + w0.z * m0.z + w0.w * m0.w
                         + w1.x * m1.x + w1.y * m1.y + w1.z * m1.z + w1.w * m1.w
                         + w2.x * m2.x + w2.y * m2.y + w2.z * m2.z + w2.w * m2.w
                         + w3.x * m3.x + w3.y * m3.y + w3.z * m3.z + w3.w * m3.w;
            }
        }
        #pragma unroll
        for (int pi = 0; pi < 6; ++pi)
            xls[(pb6 + pi) * 68 + lane] = acc[pi];   // banks (4p+j)%32: 2-way
    }

    // ---- Seeds: d_k[jl] = c1v*cos(k*theta); c1v folded into seeds ----
    float A[8], ce[8], co[8];
    {
        float4 pr0 = *(const float4*)&P[lane * 64 + jb];
        float4 pr1 = *(const float4*)&P[lane * 64 + jb + 4];
        float pv[8] = {pr0.x, pr0.y, pr0.z, pr0.w, pr1.x, pr1.y, pr1.z, pr1.w};
        float k1f = (float)k1, k2f = (float)k2s;
        #pragma unroll
        for (int jl = 0; jl < 8; ++jl) {
            float T  = (float)(lane * 64 + jb + jl + 2);
            float rT = __builtin_amdgcn_rcpf(T);
            A[jl]    = 2.0f * cos_revr(1.0f, rT);
            float c1 = cos_revr(k1f, rT) * pv[jl];
            ce[jl]   = cos_revr(k2f, rT) * c1;          // d_{k2s}
            co[jl]   = cos_revr(k2f - 1.0f, rT) * c1;   // d_{k2s-1}
        }
    }
    __syncthreads();                    // sync2: xls visible

    // base pointers: all inner offsets become compile-time immediates
    float* pw = part + w * 512 + lane;          // part[w][s][lane], +s*64
    const float* pr = part + t;                 // reduce base, +ww*512
    float* outp = out + ((size_t)k1 * NW + k2s) * 64 + t;   // +sub*512

    // ---- Phase D: 6 subs x 8 k2 steps; xs = uniform LDS b128 broadcast ----
    #pragma unroll
    for (int sub = 0; sub < 6; ++sub) {
        #pragma unroll
        for (int m = 0; m < 4; ++m) {
            {   // even step: current = ce, advance co
                const int s = 2 * m;
                const int k2i = sub * 8 + s;    // compile-time
                const float4* xq = (const float4*)&xls[k2i * 68 + jb];  // uniform
                float4 q0 = xq[0], q1 = xq[1];
                float xs[8] = {q0.x, q0.y, q0.z, q0.w, q1.x, q1.y, q1.z, q1.w};
                float pa = 0.f, pb = 0.f;       // two 4-deep chains
                #pragma unroll
                for (int jl = 0; jl < 4; ++jl) {
                    pa     = fmaf(xs[jl], ce[jl], pa);
                    co[jl] = fmaf(A[jl], ce[jl], -co[jl]);
                }
                #pragma unroll
                for (int jl = 4; jl < 8; ++jl) {
                    pb     = fmaf(xs[jl], ce[jl], pb);
                    co[jl] = fmaf(A[jl], ce[jl], -co[jl]);
                }
                pw[s * 64] = pa + pb;           // ds_write, imm offset
            }
            {   // odd step: current = co, advance ce
                const int s = 2 * m + 1;
                const int k2i = sub * 8 + s;
                const float4* xq = (const float4*)&xls[k2i * 68 + jb];  // uniform
                float4 q0 = xq[0], q1 = xq[1];
                float xs[8] = {q0.x, q0.y, q0.z, q0.w, q1.x, q1.y, q1.z, q1.w};
                float pa = 0.f, pb = 0.f;
                #pragma unroll
                for (int jl = 0; jl < 4; ++jl) {
                    pa     = fmaf(xs[jl], co[jl], pa);
                    ce[jl] = fmaf(A[jl], co[jl], -ce[jl]);
                }
                #pragma unroll
                for (int jl = 4; jl < 8; ++jl) {
                    pb     = fmaf(xs[jl], co[jl], pb);
                    ce[jl] = fmaf(A[jl], co[jl], -ce[jl]);
                }
                pw[s * 64] = pa + pb;           // ds_write, imm offset
            }
        }
        __syncthreads();                // all 8 wave-partial slices written
        {   // reduce 8 wave-partials; imm-offset reads; coalesced store
            float r = pr[0]    + pr[512]  + pr[1024] + pr[1536]
                    + pr[2048] + pr[2560] + pr[3072] + pr[3584];
            outp[sub * 512] = r;
        }
        __syncthreads();                // part reusable next sub
    }
}

extern "C" void kernel_launch(void* const* d_in, const int* in_sizes, int n_in,
                              void* d_out, int out_size, void* d_ws, size_t ws_size,
                              hipStream_t stream) {
    const float* grid = (const float*)d_in[0];   // [193,193,64]
    const float* Mw   = (const float*)d_in[1];   // [64,64]
    const float* P    = (const float*)d_in[2];   // [64,64]
    float* out = (float*)d_out;                  // [36864,64]
    (void)d_ws; (void)ws_size;                   // workspace unused

    k_fused<<<NMAIN, 512, 0, stream>>>(grid, Mw, P, out);
}